// Round 5
// baseline (221.346 us; speedup 1.0000x reference)
//
#include <hip/hip_runtime.h>
#include <math.h>

#define BB   64
#define KK   128
#define HH   64
#define WW   64
#define HW   (HH*WW)      // 4096
#define NBOX 256
#define NCLS (BB*KK)      // 8192

// MEASUREMENT ROUND: exact R2 structure (fastest, 201.2us), but main_kernel is
// launched TWICE. Idempotent: same inputs -> same ws values. The total-time
// delta vs R2 measures main_kernel's true in-graph duration, which the rocprof
// top-5 cutoff (harness 512MB poison-fills at ~77us) hides from us.

// Blocks [0, NCLS): per-(b,k) max over plane -> BCE term -> ws[blk]
// Blocks [NCLS, NCLS+NBOX): per-box sigmoid in/out sums -> ws[NCLS+n]
__global__ __launch_bounds__(256) void main_kernel(
    const float* __restrict__ cams,
    const float* __restrict__ gt,
    const int* __restrict__ box_b, const int* __restrict__ box_c,
    const int* __restrict__ by0, const int* __restrict__ by1,
    const int* __restrict__ bx0, const int* __restrict__ bx1,
    float* __restrict__ ws)
{
    const int blk = blockIdx.x;
    const int t   = threadIdx.x;
    __shared__ float red[8];

    if (blk < NCLS) {
        // ---- cls path: max over 4096 floats ----
        const float4* p = (const float4*)(cams + (size_t)blk * HW);
        float m = -INFINITY;
        #pragma unroll
        for (int j = 0; j < 4; ++j) {
            float4 v = p[t + 256 * j];            // coalesced, 16B/lane
            m = fmaxf(m, fmaxf(fmaxf(v.x, v.y), fmaxf(v.z, v.w)));
        }
        #pragma unroll
        for (int off = 32; off >= 1; off >>= 1)
            m = fmaxf(m, __shfl_down(m, off, 64));
        const int wave = t >> 6;
        if ((t & 63) == 0) red[wave] = m;
        __syncthreads();
        if (t == 0) {
            float z = fmaxf(fmaxf(red[0], red[1]), fmaxf(red[2], red[3]));
            float y = gt[blk];
            // stable BCE-with-logits
            ws[blk] = fmaxf(z, 0.f) - z * y + log1pf(expf(-fabsf(z)));
        }
    } else {
        // ---- box path ----
        const int n  = blk - NCLS;
        const int b  = box_b[n];
        const int c  = box_c[n];
        const int y0 = by0[n], y1 = by1[n];
        const int x0 = bx0[n], x1 = bx1[n];
        const float4* p = (const float4*)(cams + ((size_t)b * KK + c) * HW);

        float ins = 0.f, outs = 0.f;
        #pragma unroll
        for (int j = 0; j < 4; ++j) {
            const int i4  = t + 256 * j;
            float4 v = p[i4];
            const int pix = i4 * 4;          // 4 consecutive pixels, same row
            const int row = pix >> 6;
            const int col = pix & 63;
            const bool rin = (row >= y0) && (row < y1);
            float vv[4] = {v.x, v.y, v.z, v.w};
            #pragma unroll
            for (int e = 0; e < 4; ++e) {
                float s = 1.f / (1.f + expf(-vv[e]));
                const int cc = col + e;
                const bool in = rin && (cc >= x0) && (cc < x1);
                float d = s - 1.f;
                if (in) ins  += d * d;
                else    outs += s * s;
            }
        }
        #pragma unroll
        for (int off = 32; off >= 1; off >>= 1) {
            ins  += __shfl_down(ins,  off, 64);
            outs += __shfl_down(outs, off, 64);
        }
        const int wave = t >> 6;
        if ((t & 63) == 0) { red[wave] = ins; red[4 + wave] = outs; }
        __syncthreads();
        if (t == 0) {
            float I = red[0] + red[1] + red[2] + red[3];
            float O = red[4] + red[5] + red[6] + red[7];
            float area = (float)((y1 - y0) * (x1 - x0));
            ws[NCLS + n] = I / (area + 1e-6f) + O / ((float)HW - area + 1e-6f);
        }
    }
}

// One block, 256 threads: sum 8192 BCE partials and 256 box partials.
__global__ __launch_bounds__(256) void reduce_kernel(
    const float* __restrict__ ws, float* __restrict__ out)
{
    const int t = threadIdx.x;
    __shared__ float red[8];

    float sc = 0.f;
    #pragma unroll
    for (int j = 0; j < NCLS / 256; ++j) sc += ws[t + 256 * j];
    float sb = ws[NCLS + t];

    #pragma unroll
    for (int off = 32; off >= 1; off >>= 1) {
        sc += __shfl_down(sc, off, 64);
        sb += __shfl_down(sb, off, 64);
    }
    const int wave = t >> 6;
    if ((t & 63) == 0) { red[wave] = sc; red[4 + wave] = sb; }
    __syncthreads();
    if (t == 0) {
        float cls = red[0] + red[1] + red[2] + red[3];
        float box = red[4] + red[5] + red[6] + red[7];
        out[0] = 1.0f * cls / (float)NCLS + 0.5f * box / (float)NBOX;
    }
}

extern "C" void kernel_launch(void* const* d_in, const int* in_sizes, int n_in,
                              void* d_out, int out_size, void* d_ws, size_t ws_size,
                              hipStream_t stream) {
    const float* cams = (const float*)d_in[0];
    const float* gt   = (const float*)d_in[1];
    const int*   bb   = (const int*)d_in[2];
    const int*   bc   = (const int*)d_in[3];
    const int*   y0   = (const int*)d_in[4];
    const int*   y1   = (const int*)d_in[5];
    const int*   x0   = (const int*)d_in[6];
    const int*   x1   = (const int*)d_in[7];
    float* ws  = (float*)d_ws;
    float* out = (float*)d_out;

    // Launched twice on purpose: measurement of main's in-graph duration via
    // total-time delta vs the single-launch R2 baseline. Idempotent & capture-safe.
    main_kernel<<<NCLS + NBOX, 256, 0, stream>>>(cams, gt, bb, bc, y0, y1, x0, x1, ws);
    main_kernel<<<NCLS + NBOX, 256, 0, stream>>>(cams, gt, bb, bc, y0, y1, x0, x1, ws);
    reduce_kernel<<<1, 256, 0, stream>>>(ws, out);
}

// Round 6
// 200.756 us; speedup vs baseline: 1.1026x; 1.1026x over previous
//
#include <hip/hip_runtime.h>
#include <math.h>

#define BB   64
#define KK   128
#define HH   64
#define WW   64
#define HW   (HH*WW)      // 4096
#define NBOX 256
#define NCLS (BB*KK)      // 8192

// ROOFLINE CANDIDATE (R2 structure, fastest measured: 201.2us total).
// R5 double-launch experiment measured main_kernel at ~20us (L3-warm),
// i.e. ~6.7 TB/s effective on the 134MB cams read — at the achievable
// fabric rate (harness's own 512MB fill runs 6.9 TB/s on this box).
// Remaining total time is harness-fixed poison-fill/restore traffic.

// Blocks [0, NCLS): per-(b,k) max over plane -> BCE term -> ws[blk]
// Blocks [NCLS, NCLS+NBOX): per-box sigmoid in/out sums -> ws[NCLS+n]
__global__ __launch_bounds__(256) void main_kernel(
    const float* __restrict__ cams,
    const float* __restrict__ gt,
    const int* __restrict__ box_b, const int* __restrict__ box_c,
    const int* __restrict__ by0, const int* __restrict__ by1,
    const int* __restrict__ bx0, const int* __restrict__ bx1,
    float* __restrict__ ws)
{
    const int blk = blockIdx.x;
    const int t   = threadIdx.x;
    __shared__ float red[8];

    if (blk < NCLS) {
        // ---- cls path: max over 4096 floats ----
        const float4* p = (const float4*)(cams + (size_t)blk * HW);
        float m = -INFINITY;
        #pragma unroll
        for (int j = 0; j < 4; ++j) {
            float4 v = p[t + 256 * j];            // coalesced, 16B/lane
            m = fmaxf(m, fmaxf(fmaxf(v.x, v.y), fmaxf(v.z, v.w)));
        }
        #pragma unroll
        for (int off = 32; off >= 1; off >>= 1)
            m = fmaxf(m, __shfl_down(m, off, 64));
        const int wave = t >> 6;
        if ((t & 63) == 0) red[wave] = m;
        __syncthreads();
        if (t == 0) {
            float z = fmaxf(fmaxf(red[0], red[1]), fmaxf(red[2], red[3]));
            float y = gt[blk];
            // stable BCE-with-logits
            ws[blk] = fmaxf(z, 0.f) - z * y + log1pf(expf(-fabsf(z)));
        }
    } else {
        // ---- box path ----
        const int n  = blk - NCLS;
        const int b  = box_b[n];
        const int c  = box_c[n];
        const int y0 = by0[n], y1 = by1[n];
        const int x0 = bx0[n], x1 = bx1[n];
        const float4* p = (const float4*)(cams + ((size_t)b * KK + c) * HW);

        float ins = 0.f, outs = 0.f;
        #pragma unroll
        for (int j = 0; j < 4; ++j) {
            const int i4  = t + 256 * j;
            float4 v = p[i4];
            const int pix = i4 * 4;          // 4 consecutive pixels, same row
            const int row = pix >> 6;
            const int col = pix & 63;
            const bool rin = (row >= y0) && (row < y1);
            float vv[4] = {v.x, v.y, v.z, v.w};
            #pragma unroll
            for (int e = 0; e < 4; ++e) {
                float s = 1.f / (1.f + expf(-vv[e]));
                const int cc = col + e;
                const bool in = rin && (cc >= x0) && (cc < x1);
                float d = s - 1.f;
                if (in) ins  += d * d;
                else    outs += s * s;
            }
        }
        #pragma unroll
        for (int off = 32; off >= 1; off >>= 1) {
            ins  += __shfl_down(ins,  off, 64);
            outs += __shfl_down(outs, off, 64);
        }
        const int wave = t >> 6;
        if ((t & 63) == 0) { red[wave] = ins; red[4 + wave] = outs; }
        __syncthreads();
        if (t == 0) {
            float I = red[0] + red[1] + red[2] + red[3];
            float O = red[4] + red[5] + red[6] + red[7];
            float area = (float)((y1 - y0) * (x1 - x0));
            ws[NCLS + n] = I / (area + 1e-6f) + O / ((float)HW - area + 1e-6f);
        }
    }
}

// One block, 256 threads: sum 8192 BCE partials and 256 box partials.
__global__ __launch_bounds__(256) void reduce_kernel(
    const float* __restrict__ ws, float* __restrict__ out)
{
    const int t = threadIdx.x;
    __shared__ float red[8];

    float sc = 0.f;
    #pragma unroll
    for (int j = 0; j < NCLS / 256; ++j) sc += ws[t + 256 * j];
    float sb = ws[NCLS + t];

    #pragma unroll
    for (int off = 32; off >= 1; off >>= 1) {
        sc += __shfl_down(sc, off, 64);
        sb += __shfl_down(sb, off, 64);
    }
    const int wave = t >> 6;
    if ((t & 63) == 0) { red[wave] = sc; red[4 + wave] = sb; }
    __syncthreads();
    if (t == 0) {
        float cls = red[0] + red[1] + red[2] + red[3];
        float box = red[4] + red[5] + red[6] + red[7];
        out[0] = 1.0f * cls / (float)NCLS + 0.5f * box / (float)NBOX;
    }
}

extern "C" void kernel_launch(void* const* d_in, const int* in_sizes, int n_in,
                              void* d_out, int out_size, void* d_ws, size_t ws_size,
                              hipStream_t stream) {
    const float* cams = (const float*)d_in[0];
    const float* gt   = (const float*)d_in[1];
    const int*   bb   = (const int*)d_in[2];
    const int*   bc   = (const int*)d_in[3];
    const int*   y0   = (const int*)d_in[4];
    const int*   y1   = (const int*)d_in[5];
    const int*   x0   = (const int*)d_in[6];
    const int*   x1   = (const int*)d_in[7];
    float* ws  = (float*)d_ws;
    float* out = (float*)d_out;

    main_kernel<<<NCLS + NBOX, 256, 0, stream>>>(cams, gt, bb, bc, y0, y1, x0, x1, ws);
    reduce_kernel<<<1, 256, 0, stream>>>(ws, out);
}